// Round 7
// baseline (295.399 us; speedup 1.0000x reference)
//
#include <hip/hip_runtime.h>
#include <math.h>

#define NS 131072
#define DIM 256
#define NCH 16                 // chains (time-chunks) per block = MFMA N
#define OUTS 16                // output steps per chain
#define WARM 12                // warmup steps (projective contraction;
                               // bf16-state noise floor makes more useless)
#define NSTEPS (WARM + OUTS)   // 28

typedef short bf16x8 __attribute__((ext_vector_type(8)));
typedef short bf16x4 __attribute__((ext_vector_type(4)));
typedef float f32x4  __attribute__((ext_vector_type(4)));

__device__ __forceinline__ unsigned short f2bf(float x) {  // RTE f32->bf16
    unsigned u = __float_as_uint(x);
    return (unsigned short)((u + 0x7FFFu + ((u >> 16) & 1u)) >> 16);
}

// Parallel-in-time HMM forward via MFMA.
// 512 blocks (2/CU) x 16 chains; chain = 16 output steps + 12 warmup steps
// from a uniform guess (diag(ps)*T is a strong projective contraction --
// lambda2/lambda1 ~ 0.04 for a random dense T -- and the state is bf16 with
// ~4e-3 steady-state noise, so 12 warmup steps are far past convergence;
// chain 0 of block 0 is re-seeded with the exact state0).
// Per block-step: S_new = ps_row ⊙ (256*T @ S), T as single RTE-bf16,
// fp32 accum in AGPRs.
//
// State LDS layout: S[ks][lq][chain][8k] so B-frag reads are stride-1
// ds_read_b128 (conflict-free) and state writes contiguous ds_write_b64.
// Normalization/std: per-wave partials {s,e1,e2} written as ONE b128 under
// the same per-step barrier (parity double-buffered); unnormalized v held
// in regs one step and written normalized during the next step, with the
// cross-wave sum done via 8 broadcast b128 reads.
__global__ void __launch_bounds__(512)
__attribute__((amdgpu_waves_per_eu(4, 4)))   // cap regs -> 4 waves/SIMD
hmm_mfma(const float* __restrict__ ps, const float* __restrict__ Tm,
         const float* __restrict__ state0, float* __restrict__ out) {
    __shared__ __align__(16) unsigned short Sbuf[2][4096];  // 2 x 8KB bf16 state
    __shared__ __align__(16) float red[2][8][NCH][4];       // [parity][wave][chain][{s,e1,e2,pad}]

    const int t    = threadIdx.x;
    const int lane = t & 63;
    const int wid  = t >> 6;      // wave 0..7 owns bins [32*wid, 32*wid+32)
    const int col  = lane & 15;   // chain index / MFMA n
    const int lq   = lane >> 4;   // k-group / C-row group
    const int blk  = blockIdx.x;
    const int binb = wid * 32;

    // ---- A-frags: T (x256) as single bf16, resident (16 frags = 64 regs) ----
    bf16x8 Ah[2][8];
    #pragma unroll
    for (int m = 0; m < 2; ++m) {
        const size_t row = (size_t)(binb + m * 16 + col);
        #pragma unroll
        for (int ks = 0; ks < 8; ++ks) {
            const float* p = Tm + row * DIM + ks * 32 + lq * 8;
            f32x4 u0 = *(const f32x4*)p;
            f32x4 u1 = *(const f32x4*)(p + 4);
            const float f[8] = {u0.x, u0.y, u0.z, u0.w, u1.x, u1.y, u1.z, u1.w};
            bf16x8 h;
            #pragma unroll
            for (int e = 0; e < 8; ++e) h[e] = (short)f2bf(f[e] * 256.0f);
            Ah[m][ks] = h;
        }
    }

    // ---- init buf0: all chains = uniform positive vector (scale-free) ----
    {
        bf16x8 one;
        #pragma unroll
        for (int e = 0; e < 8; ++e) one[e] = (short)0x3F80;
        *(bf16x8*)((char*)Sbuf + t * 16) = one;
    }
    __syncthreads();

    const int sbase = (blk * NCH + col) * OUTS - WARM;  // per-lane chain time base
    const int s0 = sbase < 0 ? 0 : sbase;
    f32x4 psc0 = *(const f32x4*)(ps + (size_t)s0 * DIM + binb + lq * 4);
    f32x4 psc1 = *(const f32x4*)(ps + (size_t)s0 * DIM + binb + 16 + lq * 4);

    const float bstep = 0.703125f;  // 180/256
    const float c0 = 30.0f + bstep * (float)(binb + lq * 4);

    f32x4 vh0 = {0.f, 0.f, 0.f, 0.f}, vh1 = {0.f, 0.f, 0.f, 0.f};

    for (int i = 0; i < NSTEPS; ++i) {
        const int cur = i & 1;

        if (i == WARM && blk == 0) {
            // re-seed chain 0 with the exact initial state (its warmup used
            // clamped ps[0] repeats).
            if (t < DIM) {
                const int k = t;
                char* p = (char*)Sbuf + cur * 8192 + (k >> 5) * 1024
                        + ((k >> 3) & 3) * 256 + (k & 7) * 2;
                *(unsigned short*)p = f2bf(state0[k]);
            }
            asm volatile("s_waitcnt lgkmcnt(0)" ::: "memory");
            __builtin_amdgcn_s_barrier();
            asm volatile("" ::: "memory");
        }

        // pin A-frags (forbid spill/remat)
        #pragma unroll
        for (int ks = 0; ks < 8; ++ks) {
            asm volatile("" : "+v"(Ah[0][ks]), "+v"(Ah[1][ks]));
        }

        // ---- B-frags first: 8 stride-1 ds_read_b128 in flight ASAP ----
        const char* sbp = (const char*)Sbuf + cur * 8192;
        bf16x8 Bf[8];
        #pragma unroll
        for (int ks = 0; ks < 8; ++ks)
            Bf[ks] = *(const bf16x8*)(sbp + ks * 1024 + lane * 16);

        // ---- deferred output of step i-1 (partials from previous parity) ----
        if (i > WARM) {
            const int pp = cur ^ 1;
            f32x4 rsum = {0.f, 0.f, 0.f, 0.f};
            #pragma unroll
            for (int w = 0; w < 8; ++w)
                rsum += *(const f32x4*)&red[pp][w][col][0];
            const float inv = 1.0f / rsum.x;
            const size_t srow = (size_t)(sbase + i - 1);
            const f32x4 o0 = vh0 * inv, o1 = vh1 * inv;
            *(f32x4*)(out + srow * DIM + binb + lq * 4) = o0;
            *(f32x4*)(out + srow * DIM + binb + 16 + lq * 4) = o1;
            if (t < NCH) {  // col == t, same rsum already in regs
                const float m1 = rsum.y * inv, m2 = rsum.z * inv;
                const float var = m2 - m1 * m1;
                out[(size_t)NS * DIM + srow] = sqrtf(var > 0.f ? var : 0.f);
            }
        }

        // prefetch next step's ps row segment (clamped)
        int snx = sbase + i + 1;
        snx = snx < 0 ? 0 : (snx > NS - 1 ? NS - 1 : snx);
        f32x4 pn0 = *(const f32x4*)(ps + (size_t)snx * DIM + binb + lq * 4);
        f32x4 pn1 = *(const f32x4*)(ps + (size_t)snx * DIM + binb + 16 + lq * 4);

        // ---- 16 MFMA: acc = T_bf16 @ S, fp32 accum ----
        f32x4 acc0 = {0.f, 0.f, 0.f, 0.f};
        f32x4 acc1 = {0.f, 0.f, 0.f, 0.f};
        #pragma unroll
        for (int ks = 0; ks < 8; ++ks) {
            acc0 = __builtin_amdgcn_mfma_f32_16x16x32_bf16(Ah[0][ks], Bf[ks], acc0, 0, 0, 0);
            acc1 = __builtin_amdgcn_mfma_f32_16x16x32_bf16(Ah[1][ks], Bf[ks], acc1, 0, 0, 0);
        }

        const f32x4 v0 = acc0 * psc0;  // bins binb+lq*4+{0..3}, chain col
        const f32x4 v1 = acc1 * psc1;  // bins binb+16+lq*4+{0..3}

        // ---- next-state bf16 write: 2 contiguous ds_write_b64 ----
        {
            char* db = (char*)Sbuf + (cur ^ 1) * 8192 + wid * 1024
                     + (lq >> 1) * 256 + col * 16 + ((4 * lq) & 7) * 2;
            bf16x4 w0, w1;
            w0[0] = (short)f2bf(v0.x); w0[1] = (short)f2bf(v0.y);
            w0[2] = (short)f2bf(v0.z); w0[3] = (short)f2bf(v0.w);
            w1[0] = (short)f2bf(v1.x); w1[1] = (short)f2bf(v1.y);
            w1[2] = (short)f2bf(v1.z); w1[3] = (short)f2bf(v1.w);
            *(bf16x4*)db = w0;
            *(bf16x4*)(db + 512) = w1;  // bins +16 -> lq' += 2
        }

        // ---- moment partials (output steps), same-barrier reduction ----
        if (i >= WARM) {
            float sp = 0.f, e1 = 0.f, e2 = 0.f;
            {
                const float fv[4] = {v0.x, v0.y, v0.z, v0.w};
                #pragma unroll
                for (int j = 0; j < 4; ++j) {
                    const float b = c0 + bstep * (float)j;
                    sp += fv[j];
                    const float tb = fv[j] * b;
                    e1 += tb; e2 += tb * b;
                }
            }
            {
                const float fv[4] = {v1.x, v1.y, v1.z, v1.w};
                #pragma unroll
                for (int j = 0; j < 4; ++j) {
                    const float b = c0 + 11.25f + bstep * (float)j;
                    sp += fv[j];
                    const float tb = fv[j] * b;
                    e1 += tb; e2 += tb * b;
                }
            }
            // reduce over the 4 lq-lanes of this chain (lanes col+16k)
            sp += __shfl_xor(sp, 16); sp += __shfl_xor(sp, 32);
            e1 += __shfl_xor(e1, 16); e1 += __shfl_xor(e1, 32);
            e2 += __shfl_xor(e2, 16); e2 += __shfl_xor(e2, 32);
            if (lane < 16) {
                f32x4 rw = {sp, e1, e2, 0.f};
                *(f32x4*)&red[cur][wid][lane][0] = rw;  // one ds_write_b128
            }
            vh0 = v0; vh1 = v1;
        }

        // single per-step barrier (orders state + red writes); no vmcnt drain
        asm volatile("s_waitcnt lgkmcnt(0)" ::: "memory");
        __builtin_amdgcn_s_barrier();
        asm volatile("" ::: "memory");

        psc0 = pn0; psc1 = pn1;
    }

    // ---- epilogue: emit the last step's output ----
    {
        const int pp = (NSTEPS - 1) & 1;
        f32x4 rsum = {0.f, 0.f, 0.f, 0.f};
        #pragma unroll
        for (int w = 0; w < 8; ++w)
            rsum += *(const f32x4*)&red[pp][w][col][0];
        const float inv = 1.0f / rsum.x;
        const size_t srow = (size_t)(sbase + NSTEPS - 1);
        const f32x4 o0 = vh0 * inv, o1 = vh1 * inv;
        *(f32x4*)(out + srow * DIM + binb + lq * 4) = o0;
        *(f32x4*)(out + srow * DIM + binb + 16 + lq * 4) = o1;
        if (t < NCH) {
            const float m1 = rsum.y * inv, m2 = rsum.z * inv;
            const float var = m2 - m1 * m1;
            out[(size_t)NS * DIM + srow] = sqrtf(var > 0.f ? var : 0.f);
        }
    }
}

extern "C" void kernel_launch(void* const* d_in, const int* in_sizes, int n_in,
                              void* d_out, int out_size, void* d_ws, size_t ws_size,
                              hipStream_t stream) {
    const float* ps     = (const float*)d_in[0];
    const float* Tm     = (const float*)d_in[1];
    const float* state0 = (const float*)d_in[2];
    float* out = (float*)d_out;

    hmm_mfma<<<dim3(NS / (NCH * OUTS)), dim3(512), 0, stream>>>(ps, Tm, state0, out);
}

// Round 8
// 122.511 us; speedup vs baseline: 2.4112x; 2.4112x over previous
//
#include <hip/hip_runtime.h>
#include <math.h>

#define NS 131072
#define DIM 256
#define NCH 16                 // chains (time-chunks) per block = MFMA N
#define OUTS 16                // output steps per chain
#define WARM 12                // warmup steps (projective contraction;
                               // bf16-state noise floor makes more useless)
#define NSTEPS (WARM + OUTS)   // 28

typedef short bf16x8 __attribute__((ext_vector_type(8)));
typedef short bf16x4 __attribute__((ext_vector_type(4)));
typedef float f32x4  __attribute__((ext_vector_type(4)));

__device__ __forceinline__ unsigned short f2bf(float x) {  // RTE f32->bf16
    unsigned u = __float_as_uint(x);
    return (unsigned short)((u + 0x7FFFu + ((u >> 16) & 1u)) >> 16);
}

// Parallel-in-time HMM forward via MFMA.
// 512 blocks (2/CU) x 16 chains; chain = 16 output steps + 12 warmup steps
// from a uniform guess (diag(ps)*T is a strong projective contraction and
// the state is bf16 with ~4e-3 steady-state noise, so 12 warmup steps are
// far past convergence; chain 0 of block 0 re-seeded with exact state0).
// Per block-step: S_new = ps_row ⊙ (256*T @ S), T as single RTE-bf16,
// fp32 accum in AGPRs.
//
// NOTE on ordering: deferred output MUST precede the B-frag ds_reads --
// hoisting the B-frags (round 7) extended their liveness across the output
// block and caused scratch spills (WRITE_SIZE 135->660 MB, 3x slowdown).
//
// State LDS layout: S[ks][lq][chain][8k] so B-frag reads are stride-1
// ds_read_b128 (conflict-free) and state writes contiguous ds_write_b64.
// Normalization/std: per-wave partials {s,e1,e2} written as ONE b128 under
// the same per-step barrier (parity double-buffered); unnormalized v held
// in regs one step and written normalized during the next step, with the
// cross-wave sum done via 8 broadcast b128 reads.
__global__ void __launch_bounds__(512)
__attribute__((amdgpu_waves_per_eu(4, 4)))   // cap regs -> 4 waves/SIMD
hmm_mfma(const float* __restrict__ ps, const float* __restrict__ Tm,
         const float* __restrict__ state0, float* __restrict__ out) {
    __shared__ __align__(16) unsigned short Sbuf[2][4096];  // 2 x 8KB bf16 state
    __shared__ __align__(16) float red[2][8][NCH][4];       // [parity][wave][chain][{s,e1,e2,pad}]

    const int t    = threadIdx.x;
    const int lane = t & 63;
    const int wid  = t >> 6;      // wave 0..7 owns bins [32*wid, 32*wid+32)
    const int col  = lane & 15;   // chain index / MFMA n
    const int lq   = lane >> 4;   // k-group / C-row group
    const int blk  = blockIdx.x;
    const int binb = wid * 32;

    // ---- A-frags: T (x256) as single bf16, resident (16 frags = 64 regs) ----
    bf16x8 Ah[2][8];
    #pragma unroll
    for (int m = 0; m < 2; ++m) {
        const size_t row = (size_t)(binb + m * 16 + col);
        #pragma unroll
        for (int ks = 0; ks < 8; ++ks) {
            const float* p = Tm + row * DIM + ks * 32 + lq * 8;
            f32x4 u0 = *(const f32x4*)p;
            f32x4 u1 = *(const f32x4*)(p + 4);
            const float f[8] = {u0.x, u0.y, u0.z, u0.w, u1.x, u1.y, u1.z, u1.w};
            bf16x8 h;
            #pragma unroll
            for (int e = 0; e < 8; ++e) h[e] = (short)f2bf(f[e] * 256.0f);
            Ah[m][ks] = h;
        }
    }

    // ---- init buf0: all chains = uniform positive vector (scale-free) ----
    {
        bf16x8 one;
        #pragma unroll
        for (int e = 0; e < 8; ++e) one[e] = (short)0x3F80;
        *(bf16x8*)((char*)Sbuf + t * 16) = one;
    }
    __syncthreads();

    const int sbase = (blk * NCH + col) * OUTS - WARM;  // per-lane chain time base
    const int s0 = sbase < 0 ? 0 : sbase;
    f32x4 psc0 = *(const f32x4*)(ps + (size_t)s0 * DIM + binb + lq * 4);
    f32x4 psc1 = *(const f32x4*)(ps + (size_t)s0 * DIM + binb + 16 + lq * 4);

    const float bstep = 0.703125f;  // 180/256
    const float c0 = 30.0f + bstep * (float)(binb + lq * 4);

    f32x4 vh0 = {0.f, 0.f, 0.f, 0.f}, vh1 = {0.f, 0.f, 0.f, 0.f};

    for (int i = 0; i < NSTEPS; ++i) {
        const int cur = i & 1;

        if (i == WARM && blk == 0) {
            // re-seed chain 0 with the exact initial state (its warmup used
            // clamped ps[0] repeats).
            if (t < DIM) {
                const int k = t;
                char* p = (char*)Sbuf + cur * 8192 + (k >> 5) * 1024
                        + ((k >> 3) & 3) * 256 + (k & 7) * 2;
                *(unsigned short*)p = f2bf(state0[k]);
            }
            asm volatile("s_waitcnt lgkmcnt(0)" ::: "memory");
            __builtin_amdgcn_s_barrier();
            asm volatile("" ::: "memory");
        }

        // pin A-frags (forbid spill/remat)
        #pragma unroll
        for (int ks = 0; ks < 8; ++ks) {
            asm volatile("" : "+v"(Ah[0][ks]), "+v"(Ah[1][ks]));
        }

        // ---- deferred output of step i-1 (partials from previous parity) ----
        // (kept BEFORE the B-frag reads: minimizes peak register liveness)
        if (i > WARM) {
            const int pp = cur ^ 1;
            f32x4 rsum = {0.f, 0.f, 0.f, 0.f};
            #pragma unroll
            for (int w = 0; w < 8; ++w)
                rsum += *(const f32x4*)&red[pp][w][col][0];
            const float inv = 1.0f / rsum.x;
            const size_t srow = (size_t)(sbase + i - 1);
            const f32x4 o0 = vh0 * inv, o1 = vh1 * inv;
            *(f32x4*)(out + srow * DIM + binb + lq * 4) = o0;
            *(f32x4*)(out + srow * DIM + binb + 16 + lq * 4) = o1;
            if (t < NCH) {  // col == t, same rsum already in regs
                const float m1 = rsum.y * inv, m2 = rsum.z * inv;
                const float var = m2 - m1 * m1;
                out[(size_t)NS * DIM + srow] = sqrtf(var > 0.f ? var : 0.f);
            }
        }

        // ---- B-frags: 8 stride-1 ds_read_b128 (conflict-free) ----
        const char* sbp = (const char*)Sbuf + cur * 8192;
        bf16x8 Bf[8];
        #pragma unroll
        for (int ks = 0; ks < 8; ++ks)
            Bf[ks] = *(const bf16x8*)(sbp + ks * 1024 + lane * 16);

        // prefetch next step's ps row segment (clamped)
        int snx = sbase + i + 1;
        snx = snx < 0 ? 0 : (snx > NS - 1 ? NS - 1 : snx);
        f32x4 pn0 = *(const f32x4*)(ps + (size_t)snx * DIM + binb + lq * 4);
        f32x4 pn1 = *(const f32x4*)(ps + (size_t)snx * DIM + binb + 16 + lq * 4);

        // ---- 16 MFMA: acc = T_bf16 @ S, fp32 accum ----
        f32x4 acc0 = {0.f, 0.f, 0.f, 0.f};
        f32x4 acc1 = {0.f, 0.f, 0.f, 0.f};
        #pragma unroll
        for (int ks = 0; ks < 8; ++ks) {
            acc0 = __builtin_amdgcn_mfma_f32_16x16x32_bf16(Ah[0][ks], Bf[ks], acc0, 0, 0, 0);
            acc1 = __builtin_amdgcn_mfma_f32_16x16x32_bf16(Ah[1][ks], Bf[ks], acc1, 0, 0, 0);
        }

        const f32x4 v0 = acc0 * psc0;  // bins binb+lq*4+{0..3}, chain col
        const f32x4 v1 = acc1 * psc1;  // bins binb+16+lq*4+{0..3}

        // ---- next-state bf16 write: 2 contiguous ds_write_b64 ----
        {
            char* db = (char*)Sbuf + (cur ^ 1) * 8192 + wid * 1024
                     + (lq >> 1) * 256 + col * 16 + ((4 * lq) & 7) * 2;
            bf16x4 w0, w1;
            w0[0] = (short)f2bf(v0.x); w0[1] = (short)f2bf(v0.y);
            w0[2] = (short)f2bf(v0.z); w0[3] = (short)f2bf(v0.w);
            w1[0] = (short)f2bf(v1.x); w1[1] = (short)f2bf(v1.y);
            w1[2] = (short)f2bf(v1.z); w1[3] = (short)f2bf(v1.w);
            *(bf16x4*)db = w0;
            *(bf16x4*)(db + 512) = w1;  // bins +16 -> lq' += 2
        }

        // ---- moment partials (output steps), same-barrier reduction ----
        if (i >= WARM) {
            float sp = 0.f, e1 = 0.f, e2 = 0.f;
            {
                const float fv[4] = {v0.x, v0.y, v0.z, v0.w};
                #pragma unroll
                for (int j = 0; j < 4; ++j) {
                    const float b = c0 + bstep * (float)j;
                    sp += fv[j];
                    const float tb = fv[j] * b;
                    e1 += tb; e2 += tb * b;
                }
            }
            {
                const float fv[4] = {v1.x, v1.y, v1.z, v1.w};
                #pragma unroll
                for (int j = 0; j < 4; ++j) {
                    const float b = c0 + 11.25f + bstep * (float)j;
                    sp += fv[j];
                    const float tb = fv[j] * b;
                    e1 += tb; e2 += tb * b;
                }
            }
            // reduce over the 4 lq-lanes of this chain (lanes col+16k)
            sp += __shfl_xor(sp, 16); sp += __shfl_xor(sp, 32);
            e1 += __shfl_xor(e1, 16); e1 += __shfl_xor(e1, 32);
            e2 += __shfl_xor(e2, 16); e2 += __shfl_xor(e2, 32);
            if (lane < 16) {
                f32x4 rw = {sp, e1, e2, 0.f};
                *(f32x4*)&red[cur][wid][lane][0] = rw;  // one ds_write_b128
            }
            vh0 = v0; vh1 = v1;
        }

        // single per-step barrier (orders state + red writes); no vmcnt drain
        asm volatile("s_waitcnt lgkmcnt(0)" ::: "memory");
        __builtin_amdgcn_s_barrier();
        asm volatile("" ::: "memory");

        psc0 = pn0; psc1 = pn1;
    }

    // ---- epilogue: emit the last step's output ----
    {
        const int pp = (NSTEPS - 1) & 1;
        f32x4 rsum = {0.f, 0.f, 0.f, 0.f};
        #pragma unroll
        for (int w = 0; w < 8; ++w)
            rsum += *(const f32x4*)&red[pp][w][col][0];
        const float inv = 1.0f / rsum.x;
        const size_t srow = (size_t)(sbase + NSTEPS - 1);
        const f32x4 o0 = vh0 * inv, o1 = vh1 * inv;
        *(f32x4*)(out + srow * DIM + binb + lq * 4) = o0;
        *(f32x4*)(out + srow * DIM + binb + 16 + lq * 4) = o1;
        if (t < NCH) {
            const float m1 = rsum.y * inv, m2 = rsum.z * inv;
            const float var = m2 - m1 * m1;
            out[(size_t)NS * DIM + srow] = sqrtf(var > 0.f ? var : 0.f);
        }
    }
}

extern "C" void kernel_launch(void* const* d_in, const int* in_sizes, int n_in,
                              void* d_out, int out_size, void* d_ws, size_t ws_size,
                              hipStream_t stream) {
    const float* ps     = (const float*)d_in[0];
    const float* Tm     = (const float*)d_in[1];
    const float* state0 = (const float*)d_in[2];
    float* out = (float*)d_out;

    hmm_mfma<<<dim3(NS / (NCH * OUTS)), dim3(512), 0, stream>>>(ps, Tm, state0, out);
}

// Round 9
// 86.424 us; speedup vs baseline: 3.4180x; 1.4176x over previous
//
#include <hip/hip_runtime.h>
#include <math.h>

#define NS 131072
#define DIM 256
#define NCH 16                 // chains (time-chunks) per block = MFMA N
#define OUTS 16                // output steps per chain
#define WARM 12                // warmup steps (projective contraction;
                               // validated on HW: absmax identical at WARM=12 vs 24)
#define NSTEPS (WARM + OUTS)   // 28

typedef short bf16x8 __attribute__((ext_vector_type(8)));
typedef short bf16x4 __attribute__((ext_vector_type(4)));
typedef float f32x4  __attribute__((ext_vector_type(4)));

__device__ __forceinline__ unsigned short f2bf(float x) {  // RTE f32->bf16
    unsigned u = __float_as_uint(x);
    return (unsigned short)((u + 0x7FFFu + ((u >> 16) & 1u)) >> 16);
}

// Parallel-in-time HMM forward via MFMA.
// 512 blocks (2/CU) x 16 chains; chain = 16 output steps + 12 warmup steps
// from a uniform guess (diag(ps)*T is a strong projective contraction and
// the state is bf16 with ~4e-3 steady-state noise; chain 0 of block 0 is
// re-seeded with the exact state0).
// Per block-step: S_new = ps_row ⊙ (256*T @ S), T as single RTE-bf16,
// fp32 accum in AGPRs.
//
// REGISTER-CLIFF WARNING (rounds 7/8 post-mortem): this kernel lives at the
// 128-reg cap of waves_per_eu(4,4). Any extra f32x4 liveness in the step
// loop (hoisted B-frags, vectorized rsum) causes scratch spills visible as
// WRITE_SIZE 135 -> 200..660 MB and 20-200% slowdown. Keep the deferred
// output BEFORE the B-frag reads and keep the red[] path SCALAR.
//
// State LDS layout: S[ks][lq][chain][8k] so B-frag reads are stride-1
// ds_read_b128 (conflict-free) and state writes contiguous ds_write_b64.
// Normalization/std: per-wave partials {s,e1,e2} via scalar b32 LDS ops
// under the same per-step barrier (parity double-buffered); unnormalized v
// held in regs one step, written normalized during the next step.
__global__ void __launch_bounds__(512)
__attribute__((amdgpu_waves_per_eu(4, 4)))   // cap regs -> 4 waves/SIMD
hmm_mfma(const float* __restrict__ ps, const float* __restrict__ Tm,
         const float* __restrict__ state0, float* __restrict__ out) {
    __shared__ __align__(16) unsigned short Sbuf[2][4096];  // 2 x 8KB bf16 state
    __shared__ __align__(16) float red[2][8][NCH][4];       // [parity][wave][chain][{s,e1,e2,pad}]

    const int t    = threadIdx.x;
    const int lane = t & 63;
    const int wid  = t >> 6;      // wave 0..7 owns bins [32*wid, 32*wid+32)
    const int col  = lane & 15;   // chain index / MFMA n
    const int lq   = lane >> 4;   // k-group / C-row group
    const int blk  = blockIdx.x;
    const int binb = wid * 32;

    // ---- A-frags: T (x256) as single bf16, resident (16 frags = 64 regs) ----
    bf16x8 Ah[2][8];
    #pragma unroll
    for (int m = 0; m < 2; ++m) {
        const size_t row = (size_t)(binb + m * 16 + col);
        #pragma unroll
        for (int ks = 0; ks < 8; ++ks) {
            const float* p = Tm + row * DIM + ks * 32 + lq * 8;
            f32x4 u0 = *(const f32x4*)p;
            f32x4 u1 = *(const f32x4*)(p + 4);
            const float f[8] = {u0.x, u0.y, u0.z, u0.w, u1.x, u1.y, u1.z, u1.w};
            bf16x8 h;
            #pragma unroll
            for (int e = 0; e < 8; ++e) h[e] = (short)f2bf(f[e] * 256.0f);
            Ah[m][ks] = h;
        }
    }

    // ---- init buf0: all chains = uniform positive vector (scale-free) ----
    {
        bf16x8 one;
        #pragma unroll
        for (int e = 0; e < 8; ++e) one[e] = (short)0x3F80;
        *(bf16x8*)((char*)Sbuf + t * 16) = one;
    }
    __syncthreads();

    const int sbase = (blk * NCH + col) * OUTS - WARM;  // per-lane chain time base
    const int s0 = sbase < 0 ? 0 : sbase;
    f32x4 psc0 = *(const f32x4*)(ps + (size_t)s0 * DIM + binb + lq * 4);
    f32x4 psc1 = *(const f32x4*)(ps + (size_t)s0 * DIM + binb + 16 + lq * 4);

    const float bstep = 0.703125f;  // 180/256
    const float c0 = 30.0f + bstep * (float)(binb + lq * 4);

    f32x4 vh0 = {0.f, 0.f, 0.f, 0.f}, vh1 = {0.f, 0.f, 0.f, 0.f};

    for (int i = 0; i < NSTEPS; ++i) {
        const int cur = i & 1;

        if (i == WARM && blk == 0) {
            // re-seed chain 0 with the exact initial state (its warmup used
            // clamped ps[0] repeats).
            if (t < DIM) {
                const int k = t;
                char* p = (char*)Sbuf + cur * 8192 + (k >> 5) * 1024
                        + ((k >> 3) & 3) * 256 + (k & 7) * 2;
                *(unsigned short*)p = f2bf(state0[k]);
            }
            asm volatile("s_waitcnt lgkmcnt(0)" ::: "memory");
            __builtin_amdgcn_s_barrier();
            asm volatile("" ::: "memory");
        }

        // pin A-frags (forbid spill/remat)
        #pragma unroll
        for (int ks = 0; ks < 8; ++ks) {
            asm volatile("" : "+v"(Ah[0][ks]), "+v"(Ah[1][ks]));
        }

        // ---- deferred output of step i-1 (partials from previous parity) ----
        // (kept BEFORE the B-frag reads: minimizes peak register liveness)
        if (i > WARM) {
            const int pp = cur ^ 1;
            float sumv = 0.f;
            #pragma unroll
            for (int w = 0; w < 8; ++w) sumv += red[pp][w][col][0];
            const float inv = 1.0f / sumv;
            const size_t srow = (size_t)(sbase + i - 1);
            const f32x4 o0 = vh0 * inv, o1 = vh1 * inv;
            *(f32x4*)(out + srow * DIM + binb + lq * 4) = o0;
            *(f32x4*)(out + srow * DIM + binb + 16 + lq * 4) = o1;
            if (t < NCH) {  // col == t for these lanes
                float s1 = 0.f, s2 = 0.f;
                #pragma unroll
                for (int w = 0; w < 8; ++w) {
                    s1 += red[pp][w][t][1];
                    s2 += red[pp][w][t][2];
                }
                const float m1 = s1 * inv, m2 = s2 * inv;
                const float var = m2 - m1 * m1;
                out[(size_t)NS * DIM + srow] = sqrtf(var > 0.f ? var : 0.f);
            }
        }

        // ---- B-frags: 8 stride-1 ds_read_b128 (conflict-free) ----
        const char* sbp = (const char*)Sbuf + cur * 8192;
        bf16x8 Bf[8];
        #pragma unroll
        for (int ks = 0; ks < 8; ++ks)
            Bf[ks] = *(const bf16x8*)(sbp + ks * 1024 + lane * 16);

        // prefetch next step's ps row segment (clamped)
        int snx = sbase + i + 1;
        snx = snx < 0 ? 0 : (snx > NS - 1 ? NS - 1 : snx);
        f32x4 pn0 = *(const f32x4*)(ps + (size_t)snx * DIM + binb + lq * 4);
        f32x4 pn1 = *(const f32x4*)(ps + (size_t)snx * DIM + binb + 16 + lq * 4);

        // ---- 16 MFMA: acc = T_bf16 @ S, fp32 accum ----
        f32x4 acc0 = {0.f, 0.f, 0.f, 0.f};
        f32x4 acc1 = {0.f, 0.f, 0.f, 0.f};
        #pragma unroll
        for (int ks = 0; ks < 8; ++ks) {
            acc0 = __builtin_amdgcn_mfma_f32_16x16x32_bf16(Ah[0][ks], Bf[ks], acc0, 0, 0, 0);
            acc1 = __builtin_amdgcn_mfma_f32_16x16x32_bf16(Ah[1][ks], Bf[ks], acc1, 0, 0, 0);
        }

        const f32x4 v0 = acc0 * psc0;  // bins binb+lq*4+{0..3}, chain col
        const f32x4 v1 = acc1 * psc1;  // bins binb+16+lq*4+{0..3}

        // ---- next-state bf16 write: 2 contiguous ds_write_b64 ----
        {
            char* db = (char*)Sbuf + (cur ^ 1) * 8192 + wid * 1024
                     + (lq >> 1) * 256 + col * 16 + ((4 * lq) & 7) * 2;
            bf16x4 w0, w1;
            w0[0] = (short)f2bf(v0.x); w0[1] = (short)f2bf(v0.y);
            w0[2] = (short)f2bf(v0.z); w0[3] = (short)f2bf(v0.w);
            w1[0] = (short)f2bf(v1.x); w1[1] = (short)f2bf(v1.y);
            w1[2] = (short)f2bf(v1.z); w1[3] = (short)f2bf(v1.w);
            *(bf16x4*)db = w0;
            *(bf16x4*)(db + 512) = w1;  // bins +16 -> lq' += 2
        }

        // ---- moment partials (output steps), same-barrier reduction ----
        if (i >= WARM) {
            float sp = 0.f, e1 = 0.f, e2 = 0.f;
            {
                const float fv[4] = {v0.x, v0.y, v0.z, v0.w};
                #pragma unroll
                for (int j = 0; j < 4; ++j) {
                    const float b = c0 + bstep * (float)j;
                    sp += fv[j];
                    const float tb = fv[j] * b;
                    e1 += tb; e2 += tb * b;
                }
            }
            {
                const float fv[4] = {v1.x, v1.y, v1.z, v1.w};
                #pragma unroll
                for (int j = 0; j < 4; ++j) {
                    const float b = c0 + 11.25f + bstep * (float)j;
                    sp += fv[j];
                    const float tb = fv[j] * b;
                    e1 += tb; e2 += tb * b;
                }
            }
            // reduce over the 4 lq-lanes of this chain (lanes col+16k)
            sp += __shfl_xor(sp, 16); sp += __shfl_xor(sp, 32);
            e1 += __shfl_xor(e1, 16); e1 += __shfl_xor(e1, 32);
            e2 += __shfl_xor(e2, 16); e2 += __shfl_xor(e2, 32);
            if (lane < 16) {
                red[cur][wid][lane][0] = sp;
                red[cur][wid][lane][1] = e1;
                red[cur][wid][lane][2] = e2;
            }
            vh0 = v0; vh1 = v1;
        }

        // single per-step barrier (orders state + red writes); no vmcnt drain
        asm volatile("s_waitcnt lgkmcnt(0)" ::: "memory");
        __builtin_amdgcn_s_barrier();
        asm volatile("" ::: "memory");

        psc0 = pn0; psc1 = pn1;
    }

    // ---- epilogue: emit the last step's output ----
    {
        const int pp = (NSTEPS - 1) & 1;
        float sumv = 0.f;
        #pragma unroll
        for (int w = 0; w < 8; ++w) sumv += red[pp][w][col][0];
        const float inv = 1.0f / sumv;
        const size_t srow = (size_t)(sbase + NSTEPS - 1);
        const f32x4 o0 = vh0 * inv, o1 = vh1 * inv;
        *(f32x4*)(out + srow * DIM + binb + lq * 4) = o0;
        *(f32x4*)(out + srow * DIM + binb + 16 + lq * 4) = o1;
        if (t < NCH) {
            float s1 = 0.f, s2 = 0.f;
            #pragma unroll
            for (int w = 0; w < 8; ++w) {
                s1 += red[pp][w][t][1];
                s2 += red[pp][w][t][2];
            }
            const float m1 = s1 * inv, m2 = s2 * inv;
            const float var = m2 - m1 * m1;
            out[(size_t)NS * DIM + srow] = sqrtf(var > 0.f ? var : 0.f);
        }
    }
}

extern "C" void kernel_launch(void* const* d_in, const int* in_sizes, int n_in,
                              void* d_out, int out_size, void* d_ws, size_t ws_size,
                              hipStream_t stream) {
    const float* ps     = (const float*)d_in[0];
    const float* Tm     = (const float*)d_in[1];
    const float* state0 = (const float*)d_in[2];
    float* out = (float*)d_out;

    hmm_mfma<<<dim3(NS / (NCH * OUTS)), dim3(512), 0, stream>>>(ps, Tm, state0, out);
}

// Round 10
// 86.287 us; speedup vs baseline: 3.4235x; 1.0016x over previous
//
#include <hip/hip_runtime.h>
#include <math.h>

#define NS 131072
#define DIM 256
#define NCH 16                 // chains (time-chunks) per block = MFMA N
#define OUTS 16                // output steps per chain
#define WARM 8                 // warmup steps (projective contraction; absmax
                               // bit-stable 0.25 for WARM in {128,64,24,12};
                               // contraction ~0.04/step -> 8 steps leaves
                               // residual ~1e-11, far below bf16 state noise)
#define NSTEPS (WARM + OUTS)   // 24

typedef short bf16x8 __attribute__((ext_vector_type(8)));
typedef short bf16x4 __attribute__((ext_vector_type(4)));
typedef float f32x4  __attribute__((ext_vector_type(4)));

__device__ __forceinline__ unsigned short f2bf(float x) {  // RTE f32->bf16
    unsigned u = __float_as_uint(x);
    return (unsigned short)((u + 0x7FFFu + ((u >> 16) & 1u)) >> 16);
}

// Parallel-in-time HMM forward via MFMA.
// 512 blocks (2/CU) x 16 chains; chain = 16 output steps + 8 warmup steps
// from a uniform guess (diag(ps)*T is a strong projective contraction and
// the state is bf16 with ~4e-3 steady-state noise; chain 0 of block 0 is
// re-seeded with the exact state0).
// Per block-step: S_new = ps_row ⊙ (256*T @ S), T as single RTE-bf16,
// fp32 accum in AGPRs.
//
// REGISTER-CLIFF WARNING (rounds 7/8 post-mortem): this kernel lives at the
// 128-reg cap of waves_per_eu(4,4). Any extra f32x4 liveness in the step
// loop (hoisted B-frags, vectorized rsum) causes scratch spills visible as
// WRITE_SIZE 135 -> 200..660 MB and 20-200% slowdown. Keep the deferred
// output BEFORE the B-frag reads and keep the red[] path SCALAR.
//
// State LDS layout: S[ks][lq][chain][8k] so B-frag reads are stride-1
// ds_read_b128 (conflict-free) and state writes contiguous ds_write_b64.
// Normalization/std: per-wave partials {s,e1,e2} via scalar b32 LDS ops
// under the same per-step barrier (parity double-buffered); unnormalized v
// held in regs one step, written normalized during the next step.
__global__ void __launch_bounds__(512)
__attribute__((amdgpu_waves_per_eu(4, 4)))   // cap regs -> 4 waves/SIMD
hmm_mfma(const float* __restrict__ ps, const float* __restrict__ Tm,
         const float* __restrict__ state0, float* __restrict__ out) {
    __shared__ __align__(16) unsigned short Sbuf[2][4096];  // 2 x 8KB bf16 state
    __shared__ __align__(16) float red[2][8][NCH][4];       // [parity][wave][chain][{s,e1,e2,pad}]

    const int t    = threadIdx.x;
    const int lane = t & 63;
    const int wid  = t >> 6;      // wave 0..7 owns bins [32*wid, 32*wid+32)
    const int col  = lane & 15;   // chain index / MFMA n
    const int lq   = lane >> 4;   // k-group / C-row group
    const int blk  = blockIdx.x;
    const int binb = wid * 32;

    // ---- A-frags: T (x256) as single bf16, resident (16 frags = 64 regs) ----
    bf16x8 Ah[2][8];
    #pragma unroll
    for (int m = 0; m < 2; ++m) {
        const size_t row = (size_t)(binb + m * 16 + col);
        #pragma unroll
        for (int ks = 0; ks < 8; ++ks) {
            const float* p = Tm + row * DIM + ks * 32 + lq * 8;
            f32x4 u0 = *(const f32x4*)p;
            f32x4 u1 = *(const f32x4*)(p + 4);
            const float f[8] = {u0.x, u0.y, u0.z, u0.w, u1.x, u1.y, u1.z, u1.w};
            bf16x8 h;
            #pragma unroll
            for (int e = 0; e < 8; ++e) h[e] = (short)f2bf(f[e] * 256.0f);
            Ah[m][ks] = h;
        }
    }

    // ---- init buf0: all chains = uniform positive vector (scale-free) ----
    {
        bf16x8 one;
        #pragma unroll
        for (int e = 0; e < 8; ++e) one[e] = (short)0x3F80;
        *(bf16x8*)((char*)Sbuf + t * 16) = one;
    }
    __syncthreads();

    const int sbase = (blk * NCH + col) * OUTS - WARM;  // per-lane chain time base
    const int s0 = sbase < 0 ? 0 : sbase;
    f32x4 psc0 = *(const f32x4*)(ps + (size_t)s0 * DIM + binb + lq * 4);
    f32x4 psc1 = *(const f32x4*)(ps + (size_t)s0 * DIM + binb + 16 + lq * 4);

    const float bstep = 0.703125f;  // 180/256
    const float c0 = 30.0f + bstep * (float)(binb + lq * 4);

    f32x4 vh0 = {0.f, 0.f, 0.f, 0.f}, vh1 = {0.f, 0.f, 0.f, 0.f};

    for (int i = 0; i < NSTEPS; ++i) {
        const int cur = i & 1;

        if (i == WARM && blk == 0) {
            // re-seed chain 0 with the exact initial state (its warmup used
            // clamped ps[0] repeats).
            if (t < DIM) {
                const int k = t;
                char* p = (char*)Sbuf + cur * 8192 + (k >> 5) * 1024
                        + ((k >> 3) & 3) * 256 + (k & 7) * 2;
                *(unsigned short*)p = f2bf(state0[k]);
            }
            asm volatile("s_waitcnt lgkmcnt(0)" ::: "memory");
            __builtin_amdgcn_s_barrier();
            asm volatile("" ::: "memory");
        }

        // pin A-frags (forbid spill/remat)
        #pragma unroll
        for (int ks = 0; ks < 8; ++ks) {
            asm volatile("" : "+v"(Ah[0][ks]), "+v"(Ah[1][ks]));
        }

        // ---- deferred output of step i-1 (partials from previous parity) ----
        // (kept BEFORE the B-frag reads: minimizes peak register liveness)
        if (i > WARM) {
            const int pp = cur ^ 1;
            float sumv = 0.f;
            #pragma unroll
            for (int w = 0; w < 8; ++w) sumv += red[pp][w][col][0];
            const float inv = 1.0f / sumv;
            const size_t srow = (size_t)(sbase + i - 1);
            const f32x4 o0 = vh0 * inv, o1 = vh1 * inv;
            *(f32x4*)(out + srow * DIM + binb + lq * 4) = o0;
            *(f32x4*)(out + srow * DIM + binb + 16 + lq * 4) = o1;
            if (t < NCH) {  // col == t for these lanes
                float s1 = 0.f, s2 = 0.f;
                #pragma unroll
                for (int w = 0; w < 8; ++w) {
                    s1 += red[pp][w][t][1];
                    s2 += red[pp][w][t][2];
                }
                const float m1 = s1 * inv, m2 = s2 * inv;
                const float var = m2 - m1 * m1;
                out[(size_t)NS * DIM + srow] = sqrtf(var > 0.f ? var : 0.f);
            }
        }

        // ---- B-frags: 8 stride-1 ds_read_b128 (conflict-free) ----
        const char* sbp = (const char*)Sbuf + cur * 8192;
        bf16x8 Bf[8];
        #pragma unroll
        for (int ks = 0; ks < 8; ++ks)
            Bf[ks] = *(const bf16x8*)(sbp + ks * 1024 + lane * 16);

        // prefetch next step's ps row segment (clamped)
        int snx = sbase + i + 1;
        snx = snx < 0 ? 0 : (snx > NS - 1 ? NS - 1 : snx);
        f32x4 pn0 = *(const f32x4*)(ps + (size_t)snx * DIM + binb + lq * 4);
        f32x4 pn1 = *(const f32x4*)(ps + (size_t)snx * DIM + binb + 16 + lq * 4);

        // ---- 16 MFMA: acc = T_bf16 @ S, fp32 accum ----
        f32x4 acc0 = {0.f, 0.f, 0.f, 0.f};
        f32x4 acc1 = {0.f, 0.f, 0.f, 0.f};
        #pragma unroll
        for (int ks = 0; ks < 8; ++ks) {
            acc0 = __builtin_amdgcn_mfma_f32_16x16x32_bf16(Ah[0][ks], Bf[ks], acc0, 0, 0, 0);
            acc1 = __builtin_amdgcn_mfma_f32_16x16x32_bf16(Ah[1][ks], Bf[ks], acc1, 0, 0, 0);
        }

        const f32x4 v0 = acc0 * psc0;  // bins binb+lq*4+{0..3}, chain col
        const f32x4 v1 = acc1 * psc1;  // bins binb+16+lq*4+{0..3}

        // ---- next-state bf16 write: 2 contiguous ds_write_b64 ----
        {
            char* db = (char*)Sbuf + (cur ^ 1) * 8192 + wid * 1024
                     + (lq >> 1) * 256 + col * 16 + ((4 * lq) & 7) * 2;
            bf16x4 w0, w1;
            w0[0] = (short)f2bf(v0.x); w0[1] = (short)f2bf(v0.y);
            w0[2] = (short)f2bf(v0.z); w0[3] = (short)f2bf(v0.w);
            w1[0] = (short)f2bf(v1.x); w1[1] = (short)f2bf(v1.y);
            w1[2] = (short)f2bf(v1.z); w1[3] = (short)f2bf(v1.w);
            *(bf16x4*)db = w0;
            *(bf16x4*)(db + 512) = w1;  // bins +16 -> lq' += 2
        }

        // ---- moment partials (output steps), same-barrier reduction ----
        if (i >= WARM) {
            float sp = 0.f, e1 = 0.f, e2 = 0.f;
            {
                const float fv[4] = {v0.x, v0.y, v0.z, v0.w};
                #pragma unroll
                for (int j = 0; j < 4; ++j) {
                    const float b = c0 + bstep * (float)j;
                    sp += fv[j];
                    const float tb = fv[j] * b;
                    e1 += tb; e2 += tb * b;
                }
            }
            {
                const float fv[4] = {v1.x, v1.y, v1.z, v1.w};
                #pragma unroll
                for (int j = 0; j < 4; ++j) {
                    const float b = c0 + 11.25f + bstep * (float)j;
                    sp += fv[j];
                    const float tb = fv[j] * b;
                    e1 += tb; e2 += tb * b;
                }
            }
            // reduce over the 4 lq-lanes of this chain (lanes col+16k)
            sp += __shfl_xor(sp, 16); sp += __shfl_xor(sp, 32);
            e1 += __shfl_xor(e1, 16); e1 += __shfl_xor(e1, 32);
            e2 += __shfl_xor(e2, 16); e2 += __shfl_xor(e2, 32);
            if (lane < 16) {
                red[cur][wid][lane][0] = sp;
                red[cur][wid][lane][1] = e1;
                red[cur][wid][lane][2] = e2;
            }
            vh0 = v0; vh1 = v1;
        }

        // single per-step barrier (orders state + red writes); no vmcnt drain
        asm volatile("s_waitcnt lgkmcnt(0)" ::: "memory");
        __builtin_amdgcn_s_barrier();
        asm volatile("" ::: "memory");

        psc0 = pn0; psc1 = pn1;
    }

    // ---- epilogue: emit the last step's output ----
    {
        const int pp = (NSTEPS - 1) & 1;
        float sumv = 0.f;
        #pragma unroll
        for (int w = 0; w < 8; ++w) sumv += red[pp][w][col][0];
        const float inv = 1.0f / sumv;
        const size_t srow = (size_t)(sbase + NSTEPS - 1);
        const f32x4 o0 = vh0 * inv, o1 = vh1 * inv;
        *(f32x4*)(out + srow * DIM + binb + lq * 4) = o0;
        *(f32x4*)(out + srow * DIM + binb + 16 + lq * 4) = o1;
        if (t < NCH) {
            float s1 = 0.f, s2 = 0.f;
            #pragma unroll
            for (int w = 0; w < 8; ++w) {
                s1 += red[pp][w][t][1];
                s2 += red[pp][w][t][2];
            }
            const float m1 = s1 * inv, m2 = s2 * inv;
            const float var = m2 - m1 * m1;
            out[(size_t)NS * DIM + srow] = sqrtf(var > 0.f ? var : 0.f);
        }
    }
}

extern "C" void kernel_launch(void* const* d_in, const int* in_sizes, int n_in,
                              void* d_out, int out_size, void* d_ws, size_t ws_size,
                              hipStream_t stream) {
    const float* ps     = (const float*)d_in[0];
    const float* Tm     = (const float*)d_in[1];
    const float* state0 = (const float*)d_in[2];
    float* out = (float*)d_out;

    hmm_mfma<<<dim3(NS / (NCH * OUTS)), dim3(512), 0, stream>>>(ps, Tm, state0, out);
}

// Round 11
// 80.885 us; speedup vs baseline: 3.6521x; 1.0668x over previous
//
#include <hip/hip_runtime.h>
#include <math.h>

#define NS 131072
#define DIM 256
#define NCH 16                 // chains (time-chunks) per block = MFMA N
#define OUTS 16                // output steps per chain
#define WARM 8                 // warmup steps (validated: absmax bit-stable
                               // 0.25 for WARM in {128,64,24,12,8})
#define NSTEPS (WARM + OUTS)   // 24
#define OSTRIDE 260            // ostage row stride in floats (1040B: 16B-aligned,
                               // 260 mod 32 = 4 -> rows spread across banks)

typedef short bf16x8 __attribute__((ext_vector_type(8)));
typedef short bf16x4 __attribute__((ext_vector_type(4)));
typedef float f32x4  __attribute__((ext_vector_type(4)));

__device__ __forceinline__ unsigned short f2bf(float x) {  // RTE f32->bf16
    unsigned u = __float_as_uint(x);
    return (unsigned short)((u + 0x7FFFu + ((u >> 16) & 1u)) >> 16);
}

// Parallel-in-time HMM forward via MFMA.
// 512 blocks (2/CU) x 16 chains; chain = 16 output steps + 8 warmup steps.
// Per block-step: S_new = ps_row ⊙ (256*T @ S), T as single RTE-bf16,
// fp32 accum in AGPRs.
//
// REGISTER-CLIFF WARNING (rounds 7/8): lives at the 128-reg cap of
// waves_per_eu(4,4). Extra f32x4 liveness in the step loop => scratch
// spills (WRITE_SIZE 135 -> 200..660 MB). Keep deferred output BEFORE the
// B-frag reads; keep the red[] path SCALAR.
//
// OUTPUT STREAMING (round 11): direct stores wrote 32 scattered 64B pieces
// per output row (16KB stride across chains) -> HBM row-thrash, measured
// ~2.9 TB/s pattern ceiling. Now: normalized rows go to LDS ostage (parity
// double-buffered); one step later each wave streams 2 FULL rows as
// contiguous 1KB wave-stores. v(i) -> normalize@i+1 -> HBM@i+2.
__global__ void __launch_bounds__(512)
__attribute__((amdgpu_waves_per_eu(4, 4)))   // cap regs -> 4 waves/SIMD
hmm_mfma(const float* __restrict__ ps, const float* __restrict__ Tm,
         const float* __restrict__ state0, float* __restrict__ out) {
    __shared__ __align__(16) unsigned short Sbuf[2][4096];  // 2 x 8KB bf16 state
    __shared__ __align__(16) float red[2][8][NCH][4];       // [parity][wave][chain][{s,e1,e2,pad}]
    __shared__ __align__(16) float ostage[2][NCH][OSTRIDE]; // staged output rows

    const int t    = threadIdx.x;
    const int lane = t & 63;
    const int wid  = t >> 6;      // wave 0..7 owns bins [32*wid, 32*wid+32)
    const int col  = lane & 15;   // chain index / MFMA n
    const int lq   = lane >> 4;   // k-group / C-row group
    const int blk  = blockIdx.x;
    const int binb = wid * 32;

    // ---- A-frags: T (x256) as single bf16, resident (16 frags = 64 regs) ----
    bf16x8 Ah[2][8];
    #pragma unroll
    for (int m = 0; m < 2; ++m) {
        const size_t row = (size_t)(binb + m * 16 + col);
        #pragma unroll
        for (int ks = 0; ks < 8; ++ks) {
            const float* p = Tm + row * DIM + ks * 32 + lq * 8;
            f32x4 u0 = *(const f32x4*)p;
            f32x4 u1 = *(const f32x4*)(p + 4);
            const float f[8] = {u0.x, u0.y, u0.z, u0.w, u1.x, u1.y, u1.z, u1.w};
            bf16x8 h;
            #pragma unroll
            for (int e = 0; e < 8; ++e) h[e] = (short)f2bf(f[e] * 256.0f);
            Ah[m][ks] = h;
        }
    }

    // ---- init buf0: all chains = uniform positive vector (scale-free) ----
    {
        bf16x8 one;
        #pragma unroll
        for (int e = 0; e < 8; ++e) one[e] = (short)0x3F80;
        *(bf16x8*)((char*)Sbuf + t * 16) = one;
    }
    __syncthreads();

    const int sbase = (blk * NCH + col) * OUTS - WARM;  // per-lane chain time base
    const int s0 = sbase < 0 ? 0 : sbase;
    f32x4 psc0 = *(const f32x4*)(ps + (size_t)s0 * DIM + binb + lq * 4);
    f32x4 psc1 = *(const f32x4*)(ps + (size_t)s0 * DIM + binb + 16 + lq * 4);

    const float bstep = 0.703125f;  // 180/256
    const float c0 = 30.0f + bstep * (float)(binb + lq * 4);

    f32x4 vh0 = {0.f, 0.f, 0.f, 0.f}, vh1 = {0.f, 0.f, 0.f, 0.f};

    for (int i = 0; i < NSTEPS; ++i) {
        const int cur = i & 1;

        if (i == WARM && blk == 0) {
            // re-seed chain 0 with the exact initial state (its warmup used
            // clamped ps[0] repeats).
            if (t < DIM) {
                const int k = t;
                char* p = (char*)Sbuf + cur * 8192 + (k >> 5) * 1024
                        + ((k >> 3) & 3) * 256 + (k & 7) * 2;
                *(unsigned short*)p = f2bf(state0[k]);
            }
            asm volatile("s_waitcnt lgkmcnt(0)" ::: "memory");
            __builtin_amdgcn_s_barrier();
            asm volatile("" ::: "memory");
        }

        // pin A-frags (forbid spill/remat)
        #pragma unroll
        for (int ks = 0; ks < 8; ++ks) {
            asm volatile("" : "+v"(Ah[0][ks]), "+v"(Ah[1][ks]));
        }

        // ---- (a) streamed store of step i-2's rows from ostage[i&1] ----
        // each wave stores 2 full rows as contiguous 1KB wave-stores
        if (i >= WARM + 2) {
            const int q  = i & 1;
            const int r0 = wid * 2;
            const int oi = i - 2 - WARM;
            const float* orow = &ostage[q][r0][0];
            const f32x4 a0 = *(const f32x4*)(orow + lane * 4);
            const f32x4 a1 = *(const f32x4*)(orow + OSTRIDE + lane * 4);
            const size_t gr = (size_t)(blk * NCH + r0) * OUTS + oi;
            *(f32x4*)(out + gr * DIM + lane * 4) = a0;
            *(f32x4*)(out + (gr + OUTS) * DIM + lane * 4) = a1;
        }

        // ---- (b) deferred normalize of step i-1 -> ostage[(i-1)&1] ----
        // (kept BEFORE the B-frag reads: minimizes peak register liveness)
        if (i > WARM) {
            const int pp = cur ^ 1;
            float sumv = 0.f;
            #pragma unroll
            for (int w = 0; w < 8; ++w) sumv += red[pp][w][col][0];
            const float inv = 1.0f / sumv;
            const f32x4 o0 = vh0 * inv, o1 = vh1 * inv;
            *(f32x4*)(&ostage[pp][col][binb + lq * 4]) = o0;
            *(f32x4*)(&ostage[pp][col][binb + 16 + lq * 4]) = o1;
            if (t < NCH) {  // col == t for these lanes; std is tiny -> direct
                float s1 = 0.f, s2 = 0.f;
                #pragma unroll
                for (int w = 0; w < 8; ++w) {
                    s1 += red[pp][w][t][1];
                    s2 += red[pp][w][t][2];
                }
                const float m1 = s1 * inv, m2 = s2 * inv;
                const float var = m2 - m1 * m1;
                out[(size_t)NS * DIM + (size_t)(sbase + i - 1)] =
                    sqrtf(var > 0.f ? var : 0.f);
            }
        }

        // ---- B-frags: 8 stride-1 ds_read_b128 (conflict-free) ----
        const char* sbp = (const char*)Sbuf + cur * 8192;
        bf16x8 Bf[8];
        #pragma unroll
        for (int ks = 0; ks < 8; ++ks)
            Bf[ks] = *(const bf16x8*)(sbp + ks * 1024 + lane * 16);

        // prefetch next step's ps row segment (clamped)
        int snx = sbase + i + 1;
        snx = snx < 0 ? 0 : (snx > NS - 1 ? NS - 1 : snx);
        f32x4 pn0 = *(const f32x4*)(ps + (size_t)snx * DIM + binb + lq * 4);
        f32x4 pn1 = *(const f32x4*)(ps + (size_t)snx * DIM + binb + 16 + lq * 4);

        // ---- 16 MFMA: acc = T_bf16 @ S, fp32 accum ----
        f32x4 acc0 = {0.f, 0.f, 0.f, 0.f};
        f32x4 acc1 = {0.f, 0.f, 0.f, 0.f};
        #pragma unroll
        for (int ks = 0; ks < 8; ++ks) {
            acc0 = __builtin_amdgcn_mfma_f32_16x16x32_bf16(Ah[0][ks], Bf[ks], acc0, 0, 0, 0);
            acc1 = __builtin_amdgcn_mfma_f32_16x16x32_bf16(Ah[1][ks], Bf[ks], acc1, 0, 0, 0);
        }

        const f32x4 v0 = acc0 * psc0;  // bins binb+lq*4+{0..3}, chain col
        const f32x4 v1 = acc1 * psc1;  // bins binb+16+lq*4+{0..3}

        // ---- next-state bf16 write: 2 contiguous ds_write_b64 ----
        {
            char* db = (char*)Sbuf + (cur ^ 1) * 8192 + wid * 1024
                     + (lq >> 1) * 256 + col * 16 + ((4 * lq) & 7) * 2;
            bf16x4 w0, w1;
            w0[0] = (short)f2bf(v0.x); w0[1] = (short)f2bf(v0.y);
            w0[2] = (short)f2bf(v0.z); w0[3] = (short)f2bf(v0.w);
            w1[0] = (short)f2bf(v1.x); w1[1] = (short)f2bf(v1.y);
            w1[2] = (short)f2bf(v1.z); w1[3] = (short)f2bf(v1.w);
            *(bf16x4*)db = w0;
            *(bf16x4*)(db + 512) = w1;  // bins +16 -> lq' += 2
        }

        // ---- moment partials (output steps), same-barrier reduction ----
        if (i >= WARM) {
            float sp = 0.f, e1 = 0.f, e2 = 0.f;
            {
                const float fv[4] = {v0.x, v0.y, v0.z, v0.w};
                #pragma unroll
                for (int j = 0; j < 4; ++j) {
                    const float b = c0 + bstep * (float)j;
                    sp += fv[j];
                    const float tb = fv[j] * b;
                    e1 += tb; e2 += tb * b;
                }
            }
            {
                const float fv[4] = {v1.x, v1.y, v1.z, v1.w};
                #pragma unroll
                for (int j = 0; j < 4; ++j) {
                    const float b = c0 + 11.25f + bstep * (float)j;
                    sp += fv[j];
                    const float tb = fv[j] * b;
                    e1 += tb; e2 += tb * b;
                }
            }
            // reduce over the 4 lq-lanes of this chain (lanes col+16k)
            sp += __shfl_xor(sp, 16); sp += __shfl_xor(sp, 32);
            e1 += __shfl_xor(e1, 16); e1 += __shfl_xor(e1, 32);
            e2 += __shfl_xor(e2, 16); e2 += __shfl_xor(e2, 32);
            if (lane < 16) {
                red[cur][wid][lane][0] = sp;
                red[cur][wid][lane][1] = e1;
                red[cur][wid][lane][2] = e2;
            }
            vh0 = v0; vh1 = v1;
        }

        // single per-step barrier (orders state + red + ostage writes)
        asm volatile("s_waitcnt lgkmcnt(0)" ::: "memory");
        __builtin_amdgcn_s_barrier();
        asm volatile("" ::: "memory");

        psc0 = pn0; psc1 = pn1;
    }

    // ---- epilogue 1: stream rows oi = OUTS-2 (staged at step NSTEPS-1) ----
    {
        const int q  = NSTEPS & 1;   // == (NSTEPS-2)&1
        const int r0 = wid * 2;
        const float* orow = &ostage[q][r0][0];
        const f32x4 a0 = *(const f32x4*)(orow + lane * 4);
        const f32x4 a1 = *(const f32x4*)(orow + OSTRIDE + lane * 4);
        const size_t gr = (size_t)(blk * NCH + r0) * OUTS + (OUTS - 2);
        *(f32x4*)(out + gr * DIM + lane * 4) = a0;
        *(f32x4*)(out + (gr + OUTS) * DIM + lane * 4) = a1;
    }

    // ---- epilogue 2: final row (oi = OUTS-1), direct store (1 row/chain) ----
    {
        const int pp = (NSTEPS - 1) & 1;
        float sumv = 0.f;
        #pragma unroll
        for (int w = 0; w < 8; ++w) sumv += red[pp][w][col][0];
        const float inv = 1.0f / sumv;
        const size_t srow = (size_t)(sbase + NSTEPS - 1);
        const f32x4 o0 = vh0 * inv, o1 = vh1 * inv;
        *(f32x4*)(out + srow * DIM + binb + lq * 4) = o0;
        *(f32x4*)(out + srow * DIM + binb + 16 + lq * 4) = o1;
        if (t < NCH) {
            float s1 = 0.f, s2 = 0.f;
            #pragma unroll
            for (int w = 0; w < 8; ++w) {
                s1 += red[pp][w][t][1];
                s2 += red[pp][w][t][2];
            }
            const float m1 = s1 * inv, m2 = s2 * inv;
            const float var = m2 - m1 * m1;
            out[(size_t)NS * DIM + srow] = sqrtf(var > 0.f ? var : 0.f);
        }
    }
}

extern "C" void kernel_launch(void* const* d_in, const int* in_sizes, int n_in,
                              void* d_out, int out_size, void* d_ws, size_t ws_size,
                              hipStream_t stream) {
    const float* ps     = (const float*)d_in[0];
    const float* Tm     = (const float*)d_in[1];
    const float* state0 = (const float*)d_in[2];
    float* out = (float*)d_out;

    hmm_mfma<<<dim3(NS / (NCH * OUTS)), dim3(512), 0, stream>>>(ps, Tm, state0, out);
}